// Round 1
// baseline (969.530 us; speedup 1.0000x reference)
//
#include <hip/hip_runtime.h>

// MoE: T=8192 tokens, D=1024, E=8 experts, top-2, H=2730 (pad 2752), capacity=1024.
// Pipeline: router -> per-expert capacity rank -> gather(bf16) -> swiglu GEMM -> down GEMM.
// Workspace budget ~63 MB.

typedef float  f4  __attribute__((ext_vector_type(4)));
typedef float  f2  __attribute__((ext_vector_type(2)));
typedef __bf16 bf8v __attribute__((ext_vector_type(8)));
typedef __bf16 bf4v __attribute__((ext_vector_type(4)));
typedef unsigned int u32;
typedef u32 u4v __attribute__((ext_vector_type(4)));

#define NTOK 8192
#define DM   1024
#define NE   8
#define HD   2730
#define HP   2752
#define CAP  1024

__device__ __forceinline__ f4 mfma_bf16(bf8v a, bf8v b, f4 c) {
  return __builtin_amdgcn_mfma_f32_16x16x32_bf16(a, b, c, 0, 0, 0);
}

// ---------------- router: logits, top-2, softmax, scatter to per-expert lists ----------------
__global__ __launch_bounds__(256) void router_kernel(
    const float* __restrict__ x, const float* __restrict__ gw,
    int* __restrict__ cnt, float* __restrict__ elp, int* __restrict__ elpos) {
  __shared__ float gws[NE][DM];
  int tid = threadIdx.x;
  for (int i = tid * 4; i < NE * DM; i += 1024) {
    *reinterpret_cast<f4*>(&gws[0][i]) = *reinterpret_cast<const f4*>(gw + i);
  }
  __syncthreads();
  int lane = tid & 63;
  int wave = tid >> 6;
  int t = blockIdx.x * 4 + wave;
  const float* xr = x + (size_t)t * DM;
  float acc[NE];
#pragma unroll
  for (int e = 0; e < NE; ++e) acc[e] = 0.f;
#pragma unroll
  for (int i = 0; i < DM / 64; ++i) {
    float xv = xr[lane + 64 * i];
#pragma unroll
    for (int e = 0; e < NE; ++e) acc[e] += xv * gws[e][lane + 64 * i];
  }
#pragma unroll
  for (int e = 0; e < NE; ++e) {
    float v = acc[e];
#pragma unroll
    for (int off = 32; off > 0; off >>= 1) v += __shfl_xor(v, off);
    acc[e] = v;
  }
  if (lane == 0) {
    // top-2, ties -> lower index first (matches jax.lax.top_k)
    float l0 = -1e30f, l1 = -1e30f; int i0 = 0, i1 = 0;
#pragma unroll
    for (int e = 0; e < NE; ++e) {
      float v = acc[e];
      if (v > l0)      { l1 = l0; i1 = i0; l0 = v; i0 = e; }
      else if (v > l1) { l1 = v; i1 = e; }
    }
    // softmax over [l0, l1] then (no-op) renorm, replicated literally
    float e1 = expf(l1 - l0);
    float s  = 1.f + e1;
    float p0 = 1.f / s, p1 = e1 / s;
    float s2 = p0 + p1;
    p0 /= s2; p1 /= s2;
    int s0 = atomicAdd(&cnt[i0], 1);
    elp[i0 * 16384 + s0] = p0; elpos[i0 * 16384 + s0] = 2 * t;
    int s1 = atomicAdd(&cnt[i1], 1);
    elp[i1 * 16384 + s1] = p1; elpos[i1 * 16384 + s1] = 2 * t + 1;
  }
}

// ---------------- capacity: stable rank per expert (p desc, pos asc); rank<CAP kept ----------------
__global__ __launch_bounds__(1024) void rank_kernel(
    const int* __restrict__ cnt, const float* __restrict__ elp, const int* __restrict__ elpos,
    int* __restrict__ etok, float* __restrict__ ep, int* __restrict__ ecnt) {
  int e = blockIdx.x;
  int n = cnt[e];
  const float* P  = elp  + e * 16384;
  const int*  Pos = elpos + e * 16384;
  for (int i = threadIdx.x; i < n; i += 1024) {
    float pi = P[i]; int posi = Pos[i];
    int r = 0;
#pragma unroll 4
    for (int j = 0; j < n; ++j) {
      float pj = P[j];
      r += (pj > pi) || (pj == pi && Pos[j] < posi);
    }
    if (r < CAP) { etok[e * CAP + r] = posi; ep[e * CAP + r] = pi; }
  }
  if (threadIdx.x == 0) ecnt[e] = n < CAP ? n : CAP;
}

// ---------------- gather kept tokens -> bf16, zero-fill tail rows ----------------
__global__ __launch_bounds__(256) void gather_kernel(
    const float* __restrict__ x, const int* __restrict__ etok, const int* __restrict__ ecnt,
    __bf16* __restrict__ Xe) {
  int e = blockIdx.x >> 10;
  int r = blockIdx.x & 1023;
  __bf16* dst = Xe + ((size_t)(e * CAP + r)) * DM;
  int tid = threadIdx.x;
  bf4v o;
  if (r < ecnt[e]) {
    int tok = etok[e * CAP + r] >> 1;
    f4 v = reinterpret_cast<const f4*>(x + (size_t)tok * DM)[tid];
    o[0] = (__bf16)v[0]; o[1] = (__bf16)v[1]; o[2] = (__bf16)v[2]; o[3] = (__bf16)v[3];
  } else {
    o[0] = (__bf16)0.f; o[1] = (__bf16)0.f; o[2] = (__bf16)0.f; o[3] = (__bf16)0.f;
  }
  reinterpret_cast<bf4v*>(dst)[tid] = o;
}

// ---------------- GEMM1: H = silu(Xe Wg^T) * (Xe Wu^T), bf16 out ----------------
// tile 128x64, BK=64, 4 waves (2x2), wave tile 64x32, XOR-swizzled LDS.
__global__ __launch_bounds__(256) void gemm1_swiglu(
    const __bf16* __restrict__ Xe, const float* __restrict__ wg, const float* __restrict__ wu,
    const int* __restrict__ ecnt, __bf16* __restrict__ Hbuf) {
  int bid = blockIdx.x;                         // 2752 = 8 XCD * 344
  int wgid = (bid & 7) * 344 + (bid >> 3);      // each XCD owns one expert
  int pm = wgid & 7;
  int pn = (wgid >> 3) % 43;
  int e  = wgid / 344;
  int ne = ecnt[e];
  int m0 = pm * 128, n0 = pn * 64;
  if (m0 >= ne) return;

  __shared__ __align__(16) __bf16 As[128 * 64];
  __shared__ __align__(16) __bf16 Bgs[64 * 64];
  __shared__ __align__(16) __bf16 Bus[64 * 64];

  int tid = threadIdx.x;
  int lane = tid & 63, wave = tid >> 6;
  int wm = wave >> 1, wn = wave & 1;

  f4 accG[4][2], accU[4][2];
#pragma unroll
  for (int m = 0; m < 4; ++m)
#pragma unroll
    for (int n = 0; n < 2; ++n) { accG[m][n] = (f4){0,0,0,0}; accU[m][n] = (f4){0,0,0,0}; }

  const __bf16* Abase = Xe + ((size_t)(e * CAP + m0)) * DM;
  const float* Gbase = wg + (size_t)e * HD * DM;
  const float* Ubase = wu + (size_t)e * HD * DM;

  for (int kt = 0; kt < DM / 64; ++kt) {
    int k0 = kt * 64;
#pragma unroll
    for (int i = 0; i < 4; ++i) {                       // A: 128 rows x 64 bf16
      int c = tid + 256 * i;
      int row = c >> 3, c8 = c & 7;
      u4v v = *reinterpret_cast<const u4v*>(Abase + (size_t)row * DM + k0 + c8 * 8);
      int off = (row * 128 + c8 * 16) ^ ((row & 7) << 4);
      *reinterpret_cast<u4v*>(reinterpret_cast<char*>(As) + off) = v;
    }
#pragma unroll
    for (int i = 0; i < 2; ++i) {                       // Bg+Bu: 64 rows, fp32->bf16
      int c = tid + 256 * i;
      int row = c >> 3, c8 = c & 7;
      int ng = n0 + row;
      int off = (row * 128 + c8 * 16) ^ ((row & 7) << 4);
      bf8v gv, uv;
      if (ng < HD) {
        const float* gs = Gbase + (size_t)ng * DM + k0 + c8 * 8;
        const float* us = Ubase + (size_t)ng * DM + k0 + c8 * 8;
        f4 a0 = *reinterpret_cast<const f4*>(gs);
        f4 a1 = *reinterpret_cast<const f4*>(gs + 4);
        f4 b0 = *reinterpret_cast<const f4*>(us);
        f4 b1 = *reinterpret_cast<const f4*>(us + 4);
#pragma unroll
        for (int q = 0; q < 4; ++q) {
          gv[q] = (__bf16)a0[q]; gv[q + 4] = (__bf16)a1[q];
          uv[q] = (__bf16)b0[q]; uv[q + 4] = (__bf16)b1[q];
        }
      } else {
#pragma unroll
        for (int q = 0; q < 8; ++q) { gv[q] = (__bf16)0.f; uv[q] = (__bf16)0.f; }
      }
      *reinterpret_cast<bf8v*>(reinterpret_cast<char*>(Bgs) + off) = gv;
      *reinterpret_cast<bf8v*>(reinterpret_cast<char*>(Bus) + off) = uv;
    }
    __syncthreads();
#pragma unroll
    for (int kk = 0; kk < 2; ++kk) {
      int kb = kk * 64 + ((lane >> 4) << 4);
      bf8v af[4];
#pragma unroll
      for (int m = 0; m < 4; ++m) {
        int row = wm * 64 + m * 16 + (lane & 15);
        af[m] = *reinterpret_cast<const bf8v*>(
            reinterpret_cast<const char*>(As) + ((row * 128 + kb) ^ ((row & 7) << 4)));
      }
      bf8v bg[2], bu[2];
#pragma unroll
      for (int n = 0; n < 2; ++n) {
        int row = wn * 32 + n * 16 + (lane & 15);
        int off = (row * 128 + kb) ^ ((row & 7) << 4);
        bg[n] = *reinterpret_cast<const bf8v*>(reinterpret_cast<const char*>(Bgs) + off);
        bu[n] = *reinterpret_cast<const bf8v*>(reinterpret_cast<const char*>(Bus) + off);
      }
#pragma unroll
      for (int m = 0; m < 4; ++m)
#pragma unroll
        for (int n = 0; n < 2; ++n) {
          accG[m][n] = mfma_bf16(af[m], bg[n], accG[m][n]);
          accU[m][n] = mfma_bf16(af[m], bu[n], accU[m][n]);
        }
    }
    __syncthreads();
  }

  __bf16* hb = Hbuf + (size_t)e * CAP * HP;
#pragma unroll
  for (int m = 0; m < 4; ++m)
#pragma unroll
    for (int n = 0; n < 2; ++n)
#pragma unroll
      for (int j = 0; j < 4; ++j) {
        int row = m0 + wm * 64 + m * 16 + ((lane >> 4) << 2) + j;
        int col = n0 + wn * 32 + n * 16 + (lane & 15);
        float g = accG[m][n][j];
        float u = accU[m][n][j];
        float h = g / (1.f + expf(-g)) * u;      // silu(g)*u
        hb[(size_t)row * HP + col] = (__bf16)h;
      }
}

// ---------------- GEMM2: out[tok] += p * (H Wd^T) ----------------
__global__ __launch_bounds__(256) void gemm2_down(
    const __bf16* __restrict__ Hbuf, const float* __restrict__ wd,
    const int* __restrict__ ecnt, const int* __restrict__ etok, const float* __restrict__ ep,
    float* __restrict__ out) {
  int bid = blockIdx.x;                        // 1024 = 8 XCD * 128
  int wgid = (bid & 7) * 128 + (bid >> 3);     // each XCD owns one expert
  int pm = wgid & 7;
  int pn = (wgid >> 3) & 15;
  int e  = wgid >> 7;
  int ne = ecnt[e];
  int m0 = pm * 128, n0 = pn * 64;
  if (m0 >= ne) return;

  __shared__ __align__(16) __bf16 As[128 * 64];
  __shared__ __align__(16) __bf16 Bs[64 * 64];

  int tid = threadIdx.x;
  int lane = tid & 63, wave = tid >> 6;
  int wm = wave >> 1, wn = wave & 1;

  f4 acc[4][2];
#pragma unroll
  for (int m = 0; m < 4; ++m)
#pragma unroll
    for (int n = 0; n < 2; ++n) acc[m][n] = (f4){0,0,0,0};

  const __bf16* Abase = Hbuf + (size_t)(e * CAP + m0) * HP;
  const float* Bbase = wd + (size_t)e * DM * HD;

  for (int kt = 0; kt < HP / 64; ++kt) {       // 43 steps, K padded to 2752
    int k0 = kt * 64;
#pragma unroll
    for (int i = 0; i < 4; ++i) {
      int c = tid + 256 * i;
      int row = c >> 3, c8 = c & 7;
      u4v v = *reinterpret_cast<const u4v*>(Abase + (size_t)row * HP + k0 + c8 * 8);
      int off = (row * 128 + c8 * 16) ^ ((row & 7) << 4);
      *reinterpret_cast<u4v*>(reinterpret_cast<char*>(As) + off) = v;
    }
#pragma unroll
    for (int i = 0; i < 2; ++i) {
      int c = tid + 256 * i;
      int row = c >> 3, c8 = c & 7;
      int nn = n0 + row;                       // < 1024 always
      int kg = k0 + c8 * 8;
      int off = (row * 128 + c8 * 16) ^ ((row & 7) << 4);
      bf8v bv;
      const float* src = Bbase + (size_t)nn * HD + kg;
      if (kg + 8 <= HD) {                      // row stride 2730 floats: 8B-aligned only
        f2 q0 = *reinterpret_cast<const f2*>(src);
        f2 q1 = *reinterpret_cast<const f2*>(src + 2);
        f2 q2 = *reinterpret_cast<const f2*>(src + 4);
        f2 q3 = *reinterpret_cast<const f2*>(src + 6);
        bv[0] = (__bf16)q0[0]; bv[1] = (__bf16)q0[1]; bv[2] = (__bf16)q1[0]; bv[3] = (__bf16)q1[1];
        bv[4] = (__bf16)q2[0]; bv[5] = (__bf16)q2[1]; bv[6] = (__bf16)q3[0]; bv[7] = (__bf16)q3[1];
      } else {
#pragma unroll
        for (int q = 0; q < 8; ++q) bv[q] = (kg + q < HD) ? (__bf16)src[q] : (__bf16)0.f;
      }
      *reinterpret_cast<bf8v*>(reinterpret_cast<char*>(Bs) + off) = bv;
    }
    __syncthreads();
#pragma unroll
    for (int kk = 0; kk < 2; ++kk) {
      int kb = kk * 64 + ((lane >> 4) << 4);
      bf8v af[4];
#pragma unroll
      for (int m = 0; m < 4; ++m) {
        int row = wm * 64 + m * 16 + (lane & 15);
        af[m] = *reinterpret_cast<const bf8v*>(
            reinterpret_cast<const char*>(As) + ((row * 128 + kb) ^ ((row & 7) << 4)));
      }
      bf8v bfr[2];
#pragma unroll
      for (int n = 0; n < 2; ++n) {
        int row = wn * 32 + n * 16 + (lane & 15);
        bfr[n] = *reinterpret_cast<const bf8v*>(
            reinterpret_cast<const char*>(Bs) + ((row * 128 + kb) ^ ((row & 7) << 4)));
      }
#pragma unroll
      for (int m = 0; m < 4; ++m)
#pragma unroll
        for (int n = 0; n < 2; ++n)
          acc[m][n] = mfma_bf16(af[m], bfr[n], acc[m][n]);
    }
    __syncthreads();
  }

#pragma unroll
  for (int m = 0; m < 4; ++m)
#pragma unroll
    for (int j = 0; j < 4; ++j) {
      int row = m0 + wm * 64 + m * 16 + ((lane >> 4) << 2) + j;
      if (row < ne) {
        float p  = ep[e * CAP + row];
        int tok  = etok[e * CAP + row] >> 1;
        float* orow = out + (size_t)tok * DM;
#pragma unroll
        for (int n = 0; n < 2; ++n) {
          int col = n0 + wn * 32 + n * 16 + (lane & 15);
          atomicAdd(orow + col, acc[m][n][j] * p);   // <=2 adds/elem -> commutative, deterministic
        }
      }
    }
}

// ---------------- launch ----------------
extern "C" void kernel_launch(void* const* d_in, const int* in_sizes, int n_in,
                              void* d_out, int out_size, void* d_ws, size_t ws_size,
                              hipStream_t stream) {
  const float* x     = (const float*)d_in[0];
  const float* gw    = (const float*)d_in[1];
  const float* wgate = (const float*)d_in[2];
  const float* wup   = (const float*)d_in[3];
  const float* wdown = (const float*)d_in[4];
  float* out = (float*)d_out;
  char* ws = (char*)d_ws;

  // workspace layout (bytes), total ~63 MB
  float* elp   = (float*)(ws + 0);         // 8*16384*4 = 524288
  int*   elpos = (int*)  (ws + 524288);    // 524288
  int*   cnt   = (int*)  (ws + 1048576);   // 32 (pad 256)
  int*   etok  = (int*)  (ws + 1048832);   // 8*1024*4
  float* ep    = (float*)(ws + 1081600);   // 8*1024*4
  int*   ecnt  = (int*)  (ws + 1114368);   // 32 (pad 256)
  __bf16* Xe   = (__bf16*)(ws + 1114624);  // 8*1024*1024*2 = 16777216
  __bf16* Hbuf = (__bf16*)(ws + 17891840); // 8*1024*2752*2 = 45088768 -> end 62980608

  hipMemsetAsync(out, 0, (size_t)NTOK * DM * sizeof(float), stream);
  hipMemsetAsync(cnt, 0, NE * sizeof(int), stream);
  router_kernel<<<NTOK / 4, 256, 0, stream>>>(x, gw, cnt, elp, elpos);
  rank_kernel<<<NE, 1024, 0, stream>>>(cnt, elp, elpos, etok, ep, ecnt);
  gather_kernel<<<NE * CAP, 256, 0, stream>>>(x, etok, ecnt, Xe);
  gemm1_swiglu<<<8 * 43 * 8, 256, 0, stream>>>(Xe, wgate, wup, ecnt, Hbuf);
  gemm2_down<<<8 * 16 * 8, 256, 0, stream>>>(Hbuf, wdown, ecnt, etok, ep, out);
}

// Round 2
// 654.380 us; speedup vs baseline: 1.4816x; 1.4816x over previous
//
#include <hip/hip_runtime.h>

// MoE: T=8192 tokens, D=1024, E=8 experts, top-2, H=2730 (pad 2752), capacity=1024.
// Pipeline: router -> per-expert capacity rank (LDS u64-key) -> gather(bf16) -> swiglu GEMM -> down GEMM.

typedef float  f4  __attribute__((ext_vector_type(4)));
typedef float  f2  __attribute__((ext_vector_type(2)));
typedef __bf16 bf8v __attribute__((ext_vector_type(8)));
typedef __bf16 bf4v __attribute__((ext_vector_type(4)));
typedef unsigned int u32;
typedef unsigned long long u64;
typedef u32 u4v __attribute__((ext_vector_type(4)));

#define NTOK 8192
#define DM   1024
#define NE   8
#define HD   2730
#define HP   2752
#define CAP  1024
#define RCHUNKS 4   // i-chunks per expert in rank kernel

__device__ __forceinline__ f4 mfma_bf16(bf8v a, bf8v b, f4 c) {
  return __builtin_amdgcn_mfma_f32_16x16x32_bf16(a, b, c, 0, 0, 0);
}

// ---------------- router: logits, top-2, softmax, scatter to per-expert lists ----------------
__global__ __launch_bounds__(256) void router_kernel(
    const float* __restrict__ x, const float* __restrict__ gw,
    int* __restrict__ cnt, float* __restrict__ elp, int* __restrict__ elpos) {
  __shared__ float gws[NE][DM];
  int tid = threadIdx.x;
  for (int i = tid * 4; i < NE * DM; i += 1024) {
    *reinterpret_cast<f4*>(&gws[0][i]) = *reinterpret_cast<const f4*>(gw + i);
  }
  __syncthreads();
  int lane = tid & 63;
  int wave = tid >> 6;
  int t = blockIdx.x * 4 + wave;
  const float* xr = x + (size_t)t * DM;
  float acc[NE];
#pragma unroll
  for (int e = 0; e < NE; ++e) acc[e] = 0.f;
#pragma unroll
  for (int i = 0; i < DM / 64; ++i) {
    float xv = xr[lane + 64 * i];
#pragma unroll
    for (int e = 0; e < NE; ++e) acc[e] += xv * gws[e][lane + 64 * i];
  }
#pragma unroll
  for (int e = 0; e < NE; ++e) {
    float v = acc[e];
#pragma unroll
    for (int off = 32; off > 0; off >>= 1) v += __shfl_xor(v, off);
    acc[e] = v;
  }
  if (lane == 0) {
    // top-2, ties -> lower index first (matches jax.lax.top_k)
    float l0 = -1e30f, l1 = -1e30f; int i0 = 0, i1 = 0;
#pragma unroll
    for (int e = 0; e < NE; ++e) {
      float v = acc[e];
      if (v > l0)      { l1 = l0; i1 = i0; l0 = v; i0 = e; }
      else if (v > l1) { l1 = v; i1 = e; }
    }
    float e1 = expf(l1 - l0);
    float s  = 1.f + e1;
    float p0 = 1.f / s, p1 = e1 / s;
    float s2 = p0 + p1;
    p0 /= s2; p1 /= s2;
    int s0 = atomicAdd(&cnt[i0], 1);
    elp[i0 * 16384 + s0] = p0; elpos[i0 * 16384 + s0] = 2 * t;
    int s1 = atomicAdd(&cnt[i1], 1);
    elp[i1 * 16384 + s1] = p1; elpos[i1 * 16384 + s1] = 2 * t + 1;
  }
}

// ---------------- capacity rank: packed u64 keys in LDS, count-rank ----------------
// key = (float_bits(p) << 32) | (0xFFFFFFFF - pos): u64 '>' == (p desc, pos asc).
// n_e <= 8192 structurally (each token contributes an expert at most once) -> fits 64KB LDS.
__global__ __launch_bounds__(256) void rank_kernel(
    const int* __restrict__ cnt, const float* __restrict__ elp, const int* __restrict__ elpos,
    int* __restrict__ etok, float* __restrict__ ep, int* __restrict__ ecnt) {
  __shared__ u64 keys[8192];
  int e = blockIdx.x / RCHUNKS;
  int c = blockIdx.x % RCHUNKS;
  int n = cnt[e];
  const float* P  = elp  + e * 16384;
  const int* Pos = elpos + e * 16384;
  for (int j = threadIdx.x; j < n; j += 256) {
    u32 pb = __float_as_uint(P[j]);
    keys[j] = ((u64)pb << 32) | (u32)(0xFFFFFFFFu - (u32)Pos[j]);
  }
  __syncthreads();
  int chunk = (n + RCHUNKS - 1) / RCHUNKS;
  int i0 = c * chunk;
  int i1 = i0 + chunk; if (i1 > n) i1 = n;
  for (int i = i0 + (int)threadIdx.x; i < i1; i += 256) {
    u64 ki = keys[i];
    int r = 0;
#pragma unroll 8
    for (int j = 0; j < n; ++j) r += (keys[j] > ki);
    if (r < CAP) {
      int pos = (int)(0xFFFFFFFFu - (u32)ki);
      etok[e * CAP + r] = pos;
      ep[e * CAP + r] = __uint_as_float((u32)(ki >> 32));
    }
  }
  if (c == 0 && threadIdx.x == 0) ecnt[e] = n < CAP ? n : CAP;
}

// ---------------- gather kept tokens -> bf16, zero-fill tail rows ----------------
__global__ __launch_bounds__(256) void gather_kernel(
    const float* __restrict__ x, const int* __restrict__ etok, const int* __restrict__ ecnt,
    __bf16* __restrict__ Xe) {
  int e = blockIdx.x >> 10;
  int r = blockIdx.x & 1023;
  __bf16* dst = Xe + ((size_t)(e * CAP + r)) * DM;
  int tid = threadIdx.x;
  bf4v o;
  if (r < ecnt[e]) {
    int tok = etok[e * CAP + r] >> 1;
    f4 v = reinterpret_cast<const f4*>(x + (size_t)tok * DM)[tid];
    o[0] = (__bf16)v[0]; o[1] = (__bf16)v[1]; o[2] = (__bf16)v[2]; o[3] = (__bf16)v[3];
  } else {
    o[0] = (__bf16)0.f; o[1] = (__bf16)0.f; o[2] = (__bf16)0.f; o[3] = (__bf16)0.f;
  }
  reinterpret_cast<bf4v*>(dst)[tid] = o;
}

// ---------------- GEMM1: H = silu(Xe Wg^T) * (Xe Wu^T), bf16 out ----------------
// tile 128x64, BK=64, 4 waves (2x2), wave tile 64x32, XOR-swizzled LDS.
__global__ __launch_bounds__(256) void gemm1_swiglu(
    const __bf16* __restrict__ Xe, const float* __restrict__ wg, const float* __restrict__ wu,
    const int* __restrict__ ecnt, __bf16* __restrict__ Hbuf) {
  int bid = blockIdx.x;                         // 2752 = 8 XCD * 344
  int wgid = (bid & 7) * 344 + (bid >> 3);      // each XCD owns one expert
  int pm = wgid & 7;
  int pn = (wgid >> 3) % 43;
  int e  = wgid / 344;
  int ne = ecnt[e];
  int m0 = pm * 128, n0 = pn * 64;
  if (m0 >= ne) return;

  __shared__ __align__(16) __bf16 As[128 * 64];
  __shared__ __align__(16) __bf16 Bgs[64 * 64];
  __shared__ __align__(16) __bf16 Bus[64 * 64];

  int tid = threadIdx.x;
  int lane = tid & 63, wave = tid >> 6;
  int wm = wave >> 1, wn = wave & 1;

  f4 accG[4][2], accU[4][2];
#pragma unroll
  for (int m = 0; m < 4; ++m)
#pragma unroll
    for (int n = 0; n < 2; ++n) { accG[m][n] = (f4){0,0,0,0}; accU[m][n] = (f4){0,0,0,0}; }

  const __bf16* Abase = Xe + ((size_t)(e * CAP + m0)) * DM;
  const float* Gbase = wg + (size_t)e * HD * DM;
  const float* Ubase = wu + (size_t)e * HD * DM;

  for (int kt = 0; kt < DM / 64; ++kt) {
    int k0 = kt * 64;
#pragma unroll
    for (int i = 0; i < 4; ++i) {                       // A: 128 rows x 64 bf16
      int c = tid + 256 * i;
      int row = c >> 3, c8 = c & 7;
      u4v v = *reinterpret_cast<const u4v*>(Abase + (size_t)row * DM + k0 + c8 * 8);
      int off = (row * 128 + c8 * 16) ^ ((row & 7) << 4);
      *reinterpret_cast<u4v*>(reinterpret_cast<char*>(As) + off) = v;
    }
#pragma unroll
    for (int i = 0; i < 2; ++i) {                       // Bg+Bu: 64 rows, fp32->bf16
      int c = tid + 256 * i;
      int row = c >> 3, c8 = c & 7;
      int ng = n0 + row;
      int off = (row * 128 + c8 * 16) ^ ((row & 7) << 4);
      bf8v gv, uv;
      if (ng < HD) {
        const float* gs = Gbase + (size_t)ng * DM + k0 + c8 * 8;
        const float* us = Ubase + (size_t)ng * DM + k0 + c8 * 8;
        f4 a0 = *reinterpret_cast<const f4*>(gs);
        f4 a1 = *reinterpret_cast<const f4*>(gs + 4);
        f4 b0 = *reinterpret_cast<const f4*>(us);
        f4 b1 = *reinterpret_cast<const f4*>(us + 4);
#pragma unroll
        for (int q = 0; q < 4; ++q) {
          gv[q] = (__bf16)a0[q]; gv[q + 4] = (__bf16)a1[q];
          uv[q] = (__bf16)b0[q]; uv[q + 4] = (__bf16)b1[q];
        }
      } else {
#pragma unroll
        for (int q = 0; q < 8; ++q) { gv[q] = (__bf16)0.f; uv[q] = (__bf16)0.f; }
      }
      *reinterpret_cast<bf8v*>(reinterpret_cast<char*>(Bgs) + off) = gv;
      *reinterpret_cast<bf8v*>(reinterpret_cast<char*>(Bus) + off) = uv;
    }
    __syncthreads();
#pragma unroll
    for (int kk = 0; kk < 2; ++kk) {
      int kb = kk * 64 + ((lane >> 4) << 4);
      bf8v af[4];
#pragma unroll
      for (int m = 0; m < 4; ++m) {
        int row = wm * 64 + m * 16 + (lane & 15);
        af[m] = *reinterpret_cast<const bf8v*>(
            reinterpret_cast<const char*>(As) + ((row * 128 + kb) ^ ((row & 7) << 4)));
      }
      bf8v bg[2], bu[2];
#pragma unroll
      for (int n = 0; n < 2; ++n) {
        int row = wn * 32 + n * 16 + (lane & 15);
        int off = (row * 128 + kb) ^ ((row & 7) << 4);
        bg[n] = *reinterpret_cast<const bf8v*>(reinterpret_cast<const char*>(Bgs) + off);
        bu[n] = *reinterpret_cast<const bf8v*>(reinterpret_cast<const char*>(Bus) + off);
      }
#pragma unroll
      for (int m = 0; m < 4; ++m)
#pragma unroll
        for (int n = 0; n < 2; ++n) {
          accG[m][n] = mfma_bf16(af[m], bg[n], accG[m][n]);
          accU[m][n] = mfma_bf16(af[m], bu[n], accU[m][n]);
        }
    }
    __syncthreads();
  }

  __bf16* hb = Hbuf + (size_t)e * CAP * HP;
#pragma unroll
  for (int m = 0; m < 4; ++m)
#pragma unroll
    for (int n = 0; n < 2; ++n)
#pragma unroll
      for (int j = 0; j < 4; ++j) {
        int row = m0 + wm * 64 + m * 16 + ((lane >> 4) << 2) + j;
        int col = n0 + wn * 32 + n * 16 + (lane & 15);
        float g = accG[m][n][j];
        float u = accU[m][n][j];
        float h = g / (1.f + expf(-g)) * u;      // silu(g)*u
        hb[(size_t)row * HP + col] = (__bf16)h;
      }
}

// ---------------- GEMM2: out[tok] += p * (H Wd^T) ----------------
__global__ __launch_bounds__(256) void gemm2_down(
    const __bf16* __restrict__ Hbuf, const float* __restrict__ wd,
    const int* __restrict__ ecnt, const int* __restrict__ etok, const float* __restrict__ ep,
    float* __restrict__ out) {
  int bid = blockIdx.x;                        // 1024 = 8 XCD * 128
  int wgid = (bid & 7) * 128 + (bid >> 3);     // each XCD owns one expert
  int pm = wgid & 7;
  int pn = (wgid >> 3) & 15;
  int e  = wgid >> 7;
  int ne = ecnt[e];
  int m0 = pm * 128, n0 = pn * 64;
  if (m0 >= ne) return;

  __shared__ __align__(16) __bf16 As[128 * 64];
  __shared__ __align__(16) __bf16 Bs[64 * 64];

  int tid = threadIdx.x;
  int lane = tid & 63, wave = tid >> 6;
  int wm = wave >> 1, wn = wave & 1;

  f4 acc[4][2];
#pragma unroll
  for (int m = 0; m < 4; ++m)
#pragma unroll
    for (int n = 0; n < 2; ++n) acc[m][n] = (f4){0,0,0,0};

  const __bf16* Abase = Hbuf + (size_t)(e * CAP + m0) * HP;
  const float* Bbase = wd + (size_t)e * DM * HD;

  for (int kt = 0; kt < HP / 64; ++kt) {       // 43 steps, K padded to 2752
    int k0 = kt * 64;
#pragma unroll
    for (int i = 0; i < 4; ++i) {
      int c = tid + 256 * i;
      int row = c >> 3, c8 = c & 7;
      u4v v = *reinterpret_cast<const u4v*>(Abase + (size_t)row * HP + k0 + c8 * 8);
      int off = (row * 128 + c8 * 16) ^ ((row & 7) << 4);
      *reinterpret_cast<u4v*>(reinterpret_cast<char*>(As) + off) = v;
    }
#pragma unroll
    for (int i = 0; i < 2; ++i) {
      int c = tid + 256 * i;
      int row = c >> 3, c8 = c & 7;
      int nn = n0 + row;                       // < 1024 always
      int kg = k0 + c8 * 8;
      int off = (row * 128 + c8 * 16) ^ ((row & 7) << 4);
      bf8v bv;
      const float* src = Bbase + (size_t)nn * HD + kg;
      if (kg + 8 <= HD) {                      // row stride 2730 floats: 8B-aligned only
        f2 q0 = *reinterpret_cast<const f2*>(src);
        f2 q1 = *reinterpret_cast<const f2*>(src + 2);
        f2 q2 = *reinterpret_cast<const f2*>(src + 4);
        f2 q3 = *reinterpret_cast<const f2*>(src + 6);
        bv[0] = (__bf16)q0[0]; bv[1] = (__bf16)q0[1]; bv[2] = (__bf16)q1[0]; bv[3] = (__bf16)q1[1];
        bv[4] = (__bf16)q2[0]; bv[5] = (__bf16)q2[1]; bv[6] = (__bf16)q3[0]; bv[7] = (__bf16)q3[1];
      } else {
#pragma unroll
        for (int q = 0; q < 8; ++q) bv[q] = (kg + q < HD) ? (__bf16)src[q] : (__bf16)0.f;
      }
      *reinterpret_cast<bf8v*>(reinterpret_cast<char*>(Bs) + off) = bv;
    }
    __syncthreads();
#pragma unroll
    for (int kk = 0; kk < 2; ++kk) {
      int kb = kk * 64 + ((lane >> 4) << 4);
      bf8v af[4];
#pragma unroll
      for (int m = 0; m < 4; ++m) {
        int row = wm * 64 + m * 16 + (lane & 15);
        af[m] = *reinterpret_cast<const bf8v*>(
            reinterpret_cast<const char*>(As) + ((row * 128 + kb) ^ ((row & 7) << 4)));
      }
      bf8v bfr[2];
#pragma unroll
      for (int n = 0; n < 2; ++n) {
        int row = wn * 32 + n * 16 + (lane & 15);
        bfr[n] = *reinterpret_cast<const bf8v*>(
            reinterpret_cast<const char*>(Bs) + ((row * 128 + kb) ^ ((row & 7) << 4)));
      }
#pragma unroll
      for (int m = 0; m < 4; ++m)
#pragma unroll
        for (int n = 0; n < 2; ++n)
          acc[m][n] = mfma_bf16(af[m], bfr[n], acc[m][n]);
    }
    __syncthreads();
  }

#pragma unroll
  for (int m = 0; m < 4; ++m)
#pragma unroll
    for (int j = 0; j < 4; ++j) {
      int row = m0 + wm * 64 + m * 16 + ((lane >> 4) << 2) + j;
      if (row < ne) {
        float p  = ep[e * CAP + row];
        int tok  = etok[e * CAP + row] >> 1;
        float* orow = out + (size_t)tok * DM;
#pragma unroll
        for (int n = 0; n < 2; ++n) {
          int col = n0 + wn * 32 + n * 16 + (lane & 15);
          atomicAdd(orow + col, acc[m][n][j] * p);   // <=2 adds/elem -> commutative, deterministic
        }
      }
    }
}

// ---------------- launch ----------------
extern "C" void kernel_launch(void* const* d_in, const int* in_sizes, int n_in,
                              void* d_out, int out_size, void* d_ws, size_t ws_size,
                              hipStream_t stream) {
  const float* x     = (const float*)d_in[0];
  const float* gw    = (const float*)d_in[1];
  const float* wgate = (const float*)d_in[2];
  const float* wup   = (const float*)d_in[3];
  const float* wdown = (const float*)d_in[4];
  float* out = (float*)d_out;
  char* ws = (char*)d_ws;

  // workspace layout (bytes), total ~63 MB
  float* elp   = (float*)(ws + 0);         // 8*16384*4 = 524288
  int*   elpos = (int*)  (ws + 524288);    // 524288
  int*   cnt   = (int*)  (ws + 1048576);   // 32 (pad 256)
  int*   etok  = (int*)  (ws + 1048832);   // 8*1024*4
  float* ep    = (float*)(ws + 1081600);   // 8*1024*4
  int*   ecnt  = (int*)  (ws + 1114368);   // 32 (pad 256)
  __bf16* Xe   = (__bf16*)(ws + 1114624);  // 8*1024*1024*2 = 16777216
  __bf16* Hbuf = (__bf16*)(ws + 17891840); // 8*1024*2752*2 = 45088768 -> end 62980608

  hipMemsetAsync(out, 0, (size_t)NTOK * DM * sizeof(float), stream);
  hipMemsetAsync(cnt, 0, NE * sizeof(int), stream);
  router_kernel<<<NTOK / 4, 256, 0, stream>>>(x, gw, cnt, elp, elpos);
  rank_kernel<<<NE * RCHUNKS, 256, 0, stream>>>(cnt, elp, elpos, etok, ep, ecnt);
  gather_kernel<<<NE * CAP, 256, 0, stream>>>(x, etok, ecnt, Xe);
  gemm1_swiglu<<<8 * 43 * 8, 256, 0, stream>>>(Xe, wgate, wup, ecnt, Hbuf);
  gemm2_down<<<8 * 16 * 8, 256, 0, stream>>>(Hbuf, wdown, ecnt, etok, ep, out);
}

// Round 3
// 610.289 us; speedup vs baseline: 1.5886x; 1.0722x over previous
//
#include <hip/hip_runtime.h>

// MoE: T=8192, D=1024, E=8, top-2, H=2730 (pad 2752), capacity=1024.
// Pipeline: memset -> router -> rank -> gather(bf16) -> convert weights to bf16
//           -> gemm1 (swiglu, gload_lds+swizzle) -> gemm2 (down, gload_lds+swizzle).
// Fallback to fp32-weight GEMMs if ws_size < 189 MB.

typedef float  f4  __attribute__((ext_vector_type(4)));
typedef float  f2  __attribute__((ext_vector_type(2)));
typedef __bf16 bf8v __attribute__((ext_vector_type(8)));
typedef __bf16 bf4v __attribute__((ext_vector_type(4)));
typedef unsigned int u32;
typedef unsigned long long u64;
typedef u32 u4v __attribute__((ext_vector_type(4)));

#define NTOK 8192
#define DM   1024
#define NE   8
#define HD   2730
#define HP   2752      // padded H (K of gemm2, rows of gemm1 B)
#define CAP  1024
#define RCHUNKS 4

__device__ __forceinline__ f4 mfma_bf16(bf8v a, bf8v b, f4 c) {
  return __builtin_amdgcn_mfma_f32_16x16x32_bf16(a, b, c, 0, 0, 0);
}

// async global->LDS, 16B per lane; dest = wave-uniform base + lane*16
__device__ __forceinline__ void gl_lds16(const void* g, void* l) {
  __builtin_amdgcn_global_load_lds(
      (const __attribute__((address_space(1))) unsigned int*)g,
      (__attribute__((address_space(3))) unsigned int*)l, 16, 0, 0);
}

// ---------------- router ----------------
__global__ __launch_bounds__(256) void router_kernel(
    const float* __restrict__ x, const float* __restrict__ gw,
    int* __restrict__ cnt, float* __restrict__ elp, int* __restrict__ elpos) {
  __shared__ float gws[NE][DM];
  int tid = threadIdx.x;
  for (int i = tid * 4; i < NE * DM; i += 1024)
    *reinterpret_cast<f4*>(&gws[0][i]) = *reinterpret_cast<const f4*>(gw + i);
  __syncthreads();
  int lane = tid & 63, wave = tid >> 6;
  int t = blockIdx.x * 4 + wave;
  const float* xr = x + (size_t)t * DM;
  float acc[NE];
#pragma unroll
  for (int e = 0; e < NE; ++e) acc[e] = 0.f;
#pragma unroll
  for (int i = 0; i < DM / 64; ++i) {
    float xv = xr[lane + 64 * i];
#pragma unroll
    for (int e = 0; e < NE; ++e) acc[e] += xv * gws[e][lane + 64 * i];
  }
#pragma unroll
  for (int e = 0; e < NE; ++e) {
    float v = acc[e];
#pragma unroll
    for (int off = 32; off > 0; off >>= 1) v += __shfl_xor(v, off);
    acc[e] = v;
  }
  if (lane == 0) {
    float l0 = -1e30f, l1 = -1e30f; int i0 = 0, i1 = 0;
#pragma unroll
    for (int e = 0; e < NE; ++e) {
      float v = acc[e];
      if (v > l0)      { l1 = l0; i1 = i0; l0 = v; i0 = e; }
      else if (v > l1) { l1 = v; i1 = e; }
    }
    float e1 = expf(l1 - l0);
    float s  = 1.f + e1;
    float p0 = 1.f / s, p1 = e1 / s;
    float s2 = p0 + p1;
    p0 /= s2; p1 /= s2;
    int s0 = atomicAdd(&cnt[i0], 1);
    elp[i0 * 16384 + s0] = p0; elpos[i0 * 16384 + s0] = 2 * t;
    int s1 = atomicAdd(&cnt[i1], 1);
    elp[i1 * 16384 + s1] = p1; elpos[i1 * 16384 + s1] = 2 * t + 1;
  }
}

// ---------------- capacity rank (LDS u64 keys) ----------------
__global__ __launch_bounds__(256) void rank_kernel(
    const int* __restrict__ cnt, const float* __restrict__ elp, const int* __restrict__ elpos,
    int* __restrict__ etok, float* __restrict__ ep, int* __restrict__ ecnt) {
  __shared__ u64 keys[8192];
  int e = blockIdx.x / RCHUNKS;
  int c = blockIdx.x % RCHUNKS;
  int n = cnt[e];
  const float* P  = elp  + e * 16384;
  const int* Pos = elpos + e * 16384;
  for (int j = threadIdx.x; j < n; j += 256) {
    u32 pb = __float_as_uint(P[j]);
    keys[j] = ((u64)pb << 32) | (u32)(0xFFFFFFFFu - (u32)Pos[j]);
  }
  __syncthreads();
  int chunk = (n + RCHUNKS - 1) / RCHUNKS;
  int i0 = c * chunk;
  int i1 = i0 + chunk; if (i1 > n) i1 = n;
  for (int i = i0 + (int)threadIdx.x; i < i1; i += 256) {
    u64 ki = keys[i];
    int r = 0;
#pragma unroll 8
    for (int j = 0; j < n; ++j) r += (keys[j] > ki);
    if (r < CAP) {
      int pos = (int)(0xFFFFFFFFu - (u32)ki);
      etok[e * CAP + r] = pos;
      ep[e * CAP + r] = __uint_as_float((u32)(ki >> 32));
    }
  }
  if (c == 0 && threadIdx.x == 0) ecnt[e] = n < CAP ? n : CAP;
}

// ---------------- gather kept tokens -> bf16 ----------------
__global__ __launch_bounds__(256) void gather_kernel(
    const float* __restrict__ x, const int* __restrict__ etok, const int* __restrict__ ecnt,
    __bf16* __restrict__ Xe) {
  int e = blockIdx.x >> 10;
  int r = blockIdx.x & 1023;
  __bf16* dst = Xe + ((size_t)(e * CAP + r)) * DM;
  int tid = threadIdx.x;
  bf4v o;
  if (r < ecnt[e]) {
    int tok = etok[e * CAP + r] >> 1;
    f4 v = reinterpret_cast<const f4*>(x + (size_t)tok * DM)[tid];
    o[0] = (__bf16)v[0]; o[1] = (__bf16)v[1]; o[2] = (__bf16)v[2]; o[3] = (__bf16)v[3];
  } else {
    o[0] = (__bf16)0.f; o[1] = (__bf16)0.f; o[2] = (__bf16)0.f; o[3] = (__bf16)0.f;
  }
  reinterpret_cast<bf4v*>(dst)[tid] = o;
}

// ---------------- weight conversion fp32 -> bf16 ----------------
// gate/up: [NE][HD][DM] f32 -> [NE][HP][DM] bf16, pad rows zeroed.
__global__ __launch_bounds__(256) void convert_gu(
    const float* __restrict__ src, __bf16* __restrict__ dst) {
  int e = blockIdx.y;
  int idx = blockIdx.x * 256 + threadIdx.x;   // HP*DM/8 / gridx
  int row = idx >> 7;                          // DM/8 = 128 chunks per row
  int c = (idx & 127) << 3;
  bf8v o;
  if (row < HD) {
    const float* s = src + ((size_t)e * HD + row) * DM + c;
    f4 a = *reinterpret_cast<const f4*>(s);
    f4 b = *reinterpret_cast<const f4*>(s + 4);
#pragma unroll
    for (int q = 0; q < 4; ++q) { o[q] = (__bf16)a[q]; o[q + 4] = (__bf16)b[q]; }
  } else {
#pragma unroll
    for (int q = 0; q < 8; ++q) o[q] = (__bf16)0.f;
  }
  *reinterpret_cast<bf8v*>(dst + ((size_t)e * HP + row) * DM + c) = o;
}

// down: [NE][DM][HD] f32 -> [NE][DM][HP] bf16, pad cols zeroed. 8B-aligned src only.
__global__ __launch_bounds__(256) void convert_wd(
    const float* __restrict__ src, __bf16* __restrict__ dst) {
  int e = blockIdx.y;
  int idx = blockIdx.x * 256 + threadIdx.x;   // DM*HP/8 = 352256 -> 1376 blocks
  int row = idx / 344;                         // HP/8 = 344 chunks per row
  int c = (idx % 344) << 3;
  const float* s = src + ((size_t)e * DM + row) * HD + c;
  bf8v o;
  if (c + 8 <= HD) {
    f2 q0 = *reinterpret_cast<const f2*>(s);
    f2 q1 = *reinterpret_cast<const f2*>(s + 2);
    f2 q2 = *reinterpret_cast<const f2*>(s + 4);
    f2 q3 = *reinterpret_cast<const f2*>(s + 6);
    o[0] = (__bf16)q0[0]; o[1] = (__bf16)q0[1]; o[2] = (__bf16)q1[0]; o[3] = (__bf16)q1[1];
    o[4] = (__bf16)q2[0]; o[5] = (__bf16)q2[1]; o[6] = (__bf16)q3[0]; o[7] = (__bf16)q3[1];
  } else {
#pragma unroll
    for (int q = 0; q < 8; ++q) o[q] = (c + q < HD) ? (__bf16)s[q] : (__bf16)0.f;
  }
  *reinterpret_cast<bf8v*>(dst + ((size_t)e * DM + row) * HP + c) = o;
}

// ============ bf16 GEMMs: gload_lds staging, both-sides XOR swizzle ============
// LDS layout: row-major [rows][64 bf16] = 128B/row; byte = (row*128+colb)^((row&7)<<4).
// Staging: linear dest chunks of 1KB/wave (8 rows); per-lane global source column
// pre-swizzled: scol = ((lane&7)<<4) ^ ((lane>>3)<<4).

// GEMM1: H[e] = silu(Xe Wg^T) * (Xe Wu^T). tile 128x64(G&U), BK=64, 4 waves 2x2.
__global__ __launch_bounds__(256) void gemm1_swiglu_bf(
    const __bf16* __restrict__ Xe, const __bf16* __restrict__ wgb, const __bf16* __restrict__ wub,
    const int* __restrict__ ecnt, __bf16* __restrict__ Hbuf) {
  int bid = blockIdx.x;                         // 2752 = 8 XCD * 344
  int wgid = (bid & 7) * 344 + (bid >> 3);      // each XCD owns one expert
  int pm = wgid & 7;
  int pn = (wgid >> 3) % 43;
  int e  = wgid / 344;
  int ne = ecnt[e];
  int m0 = pm * 128, n0 = pn * 64;
  if (m0 >= ne) return;

  __shared__ __align__(16) __bf16 As[128 * 64];
  __shared__ __align__(16) __bf16 Bgs[64 * 64];
  __shared__ __align__(16) __bf16 Bus[64 * 64];

  int tid = threadIdx.x;
  int lane = tid & 63, wave = tid >> 6;
  int wm = wave >> 1, wn = wave & 1;
  int lr = lane >> 3;                       // row within 8-row chunk
  int scol = (((lane & 7) << 4) ^ (lr << 4)) >> 1;  // pre-swizzled col (elems)

  f4 accG[4][2], accU[4][2];
#pragma unroll
  for (int m = 0; m < 4; ++m)
#pragma unroll
    for (int n = 0; n < 2; ++n) { accG[m][n] = (f4){0,0,0,0}; accU[m][n] = (f4){0,0,0,0}; }

  const __bf16* Ab = Xe + ((size_t)(e * CAP + m0)) * DM;
  const __bf16* Gb = wgb + (size_t)e * HP * DM + (size_t)n0 * DM;
  const __bf16* Ub = wub + (size_t)e * HP * DM + (size_t)n0 * DM;

  for (int kt = 0; kt < DM / 64; ++kt) {
    int k0 = kt * 64;
#pragma unroll
    for (int i = 0; i < 4; ++i) {            // A: 4 chunks x (4 waves x 8 rows)
      int rb = i * 32 + wave * 8 + lr;
      gl_lds16(Ab + (size_t)rb * DM + k0 + scol,
               (char*)As + i * 4096 + wave * 1024);
    }
#pragma unroll
    for (int i = 0; i < 2; ++i) {            // Bg, Bu: 2 chunks each
      int rb = i * 32 + wave * 8 + lr;
      gl_lds16(Gb + (size_t)rb * DM + k0 + scol,
               (char*)Bgs + i * 4096 + wave * 1024);
      gl_lds16(Ub + (size_t)rb * DM + k0 + scol,
               (char*)Bus + i * 4096 + wave * 1024);
    }
    __syncthreads();
#pragma unroll
    for (int kk = 0; kk < 2; ++kk) {
      int kb = kk * 64 + ((lane >> 4) << 4);
      bf8v af[4];
#pragma unroll
      for (int m = 0; m < 4; ++m) {
        int row = wm * 64 + m * 16 + (lane & 15);
        af[m] = *reinterpret_cast<const bf8v*>(
            reinterpret_cast<const char*>(As) + ((row * 128 + kb) ^ ((row & 7) << 4)));
      }
      bf8v bg[2], bu[2];
#pragma unroll
      for (int n = 0; n < 2; ++n) {
        int row = wn * 32 + n * 16 + (lane & 15);
        int off = (row * 128 + kb) ^ ((row & 7) << 4);
        bg[n] = *reinterpret_cast<const bf8v*>(reinterpret_cast<const char*>(Bgs) + off);
        bu[n] = *reinterpret_cast<const bf8v*>(reinterpret_cast<const char*>(Bus) + off);
      }
#pragma unroll
      for (int m = 0; m < 4; ++m)
#pragma unroll
        for (int n = 0; n < 2; ++n) {
          accG[m][n] = mfma_bf16(af[m], bg[n], accG[m][n]);
          accU[m][n] = mfma_bf16(af[m], bu[n], accU[m][n]);
        }
    }
    __syncthreads();
  }

  __bf16* hb = Hbuf + (size_t)e * CAP * HP;
#pragma unroll
  for (int m = 0; m < 4; ++m)
#pragma unroll
    for (int n = 0; n < 2; ++n)
#pragma unroll
      for (int j = 0; j < 4; ++j) {
        int row = m0 + wm * 64 + m * 16 + ((lane >> 4) << 2) + j;
        int col = n0 + wn * 32 + n * 16 + (lane & 15);
        float g = accG[m][n][j];
        float u = accU[m][n][j];
        float h = g / (1.f + expf(-g)) * u;
        hb[(size_t)row * HP + col] = (__bf16)h;
      }
}

// GEMM2: out[tok] += p * (H Wd^T). tile 128x64, K=2752.
__global__ __launch_bounds__(256) void gemm2_down_bf(
    const __bf16* __restrict__ Hbuf, const __bf16* __restrict__ wdb,
    const int* __restrict__ ecnt, const int* __restrict__ etok, const float* __restrict__ ep,
    float* __restrict__ out) {
  int bid = blockIdx.x;                        // 1024 = 8 XCD * 128
  int wgid = (bid & 7) * 128 + (bid >> 3);
  int pm = wgid & 7;
  int pn = (wgid >> 3) & 15;
  int e  = wgid >> 7;
  int ne = ecnt[e];
  int m0 = pm * 128, n0 = pn * 64;
  if (m0 >= ne) return;

  __shared__ __align__(16) __bf16 As[128 * 64];
  __shared__ __align__(16) __bf16 Bs[64 * 64];

  int tid = threadIdx.x;
  int lane = tid & 63, wave = tid >> 6;
  int wm = wave >> 1, wn = wave & 1;
  int lr = lane >> 3;
  int scol = (((lane & 7) << 4) ^ (lr << 4)) >> 1;

  f4 acc[4][2];
#pragma unroll
  for (int m = 0; m < 4; ++m)
#pragma unroll
    for (int n = 0; n < 2; ++n) acc[m][n] = (f4){0,0,0,0};

  const __bf16* Ab = Hbuf + (size_t)(e * CAP + m0) * HP;
  const __bf16* Bb = wdb + (size_t)e * DM * HP + (size_t)n0 * HP;

  for (int kt = 0; kt < HP / 64; ++kt) {       // 43 steps exactly
    int k0 = kt * 64;
#pragma unroll
    for (int i = 0; i < 4; ++i) {
      int rb = i * 32 + wave * 8 + lr;
      gl_lds16(Ab + (size_t)rb * HP + k0 + scol,
               (char*)As + i * 4096 + wave * 1024);
    }
#pragma unroll
    for (int i = 0; i < 2; ++i) {
      int rb = i * 32 + wave * 8 + lr;
      gl_lds16(Bb + (size_t)rb * HP + k0 + scol,
               (char*)Bs + i * 4096 + wave * 1024);
    }
    __syncthreads();
#pragma unroll
    for (int kk = 0; kk < 2; ++kk) {
      int kb = kk * 64 + ((lane >> 4) << 4);
      bf8v af[4];
#pragma unroll
      for (int m = 0; m < 4; ++m) {
        int row = wm * 64 + m * 16 + (lane & 15);
        af[m] = *reinterpret_cast<const bf8v*>(
            reinterpret_cast<const char*>(As) + ((row * 128 + kb) ^ ((row & 7) << 4)));
      }
      bf8v bfr[2];
#pragma unroll
      for (int n = 0; n < 2; ++n) {
        int row = wn * 32 + n * 16 + (lane & 15);
        bfr[n] = *reinterpret_cast<const bf8v*>(
            reinterpret_cast<const char*>(Bs) + ((row * 128 + kb) ^ ((row & 7) << 4)));
      }
#pragma unroll
      for (int m = 0; m < 4; ++m)
#pragma unroll
        for (int n = 0; n < 2; ++n)
          acc[m][n] = mfma_bf16(af[m], bfr[n], acc[m][n]);
    }
    __syncthreads();
  }

#pragma unroll
  for (int m = 0; m < 4; ++m)
#pragma unroll
    for (int j = 0; j < 4; ++j) {
      int row = m0 + wm * 64 + m * 16 + ((lane >> 4) << 2) + j;
      if (row < ne) {
        float p  = ep[e * CAP + row];
        int tok  = etok[e * CAP + row] >> 1;
        float* orow = out + (size_t)tok * DM;
#pragma unroll
        for (int n = 0; n < 2; ++n) {
          int col = n0 + wn * 32 + n * 16 + (lane & 15);
          atomicAdd(orow + col, acc[m][n][j] * p);
        }
      }
    }
}

// ============ fallback fp32-weight GEMMs (round-2 versions) ============
__global__ __launch_bounds__(256) void gemm1_swiglu_f32(
    const __bf16* __restrict__ Xe, const float* __restrict__ wg, const float* __restrict__ wu,
    const int* __restrict__ ecnt, __bf16* __restrict__ Hbuf) {
  int bid = blockIdx.x;
  int wgid = (bid & 7) * 344 + (bid >> 3);
  int pm = wgid & 7;
  int pn = (wgid >> 3) % 43;
  int e  = wgid / 344;
  int ne = ecnt[e];
  int m0 = pm * 128, n0 = pn * 64;
  if (m0 >= ne) return;
  __shared__ __align__(16) __bf16 As[128 * 64];
  __shared__ __align__(16) __bf16 Bgs[64 * 64];
  __shared__ __align__(16) __bf16 Bus[64 * 64];
  int tid = threadIdx.x;
  int lane = tid & 63, wave = tid >> 6;
  int wm = wave >> 1, wn = wave & 1;
  f4 accG[4][2], accU[4][2];
#pragma unroll
  for (int m = 0; m < 4; ++m)
#pragma unroll
    for (int n = 0; n < 2; ++n) { accG[m][n] = (f4){0,0,0,0}; accU[m][n] = (f4){0,0,0,0}; }
  const __bf16* Abase = Xe + ((size_t)(e * CAP + m0)) * DM;
  const float* Gbase = wg + (size_t)e * HD * DM;
  const float* Ubase = wu + (size_t)e * HD * DM;
  for (int kt = 0; kt < DM / 64; ++kt) {
    int k0 = kt * 64;
#pragma unroll
    for (int i = 0; i < 4; ++i) {
      int c = tid + 256 * i;
      int row = c >> 3, c8 = c & 7;
      u4v v = *reinterpret_cast<const u4v*>(Abase + (size_t)row * DM + k0 + c8 * 8);
      int off = (row * 128 + c8 * 16) ^ ((row & 7) << 4);
      *reinterpret_cast<u4v*>(reinterpret_cast<char*>(As) + off) = v;
    }
#pragma unroll
    for (int i = 0; i < 2; ++i) {
      int c = tid + 256 * i;
      int row = c >> 3, c8 = c & 7;
      int ng = n0 + row;
      int off = (row * 128 + c8 * 16) ^ ((row & 7) << 4);
      bf8v gv, uv;
      if (ng < HD) {
        const float* gs = Gbase + (size_t)ng * DM + k0 + c8 * 8;
        const float* us = Ubase + (size_t)ng * DM + k0 + c8 * 8;
        f4 a0 = *reinterpret_cast<const f4*>(gs);
        f4 a1 = *reinterpret_cast<const f4*>(gs + 4);
        f4 b0 = *reinterpret_cast<const f4*>(us);
        f4 b1 = *reinterpret_cast<const f4*>(us + 4);
#pragma unroll
        for (int q = 0; q < 4; ++q) {
          gv[q] = (__bf16)a0[q]; gv[q + 4] = (__bf16)a1[q];
          uv[q] = (__bf16)b0[q]; uv[q + 4] = (__bf16)b1[q];
        }
      } else {
#pragma unroll
        for (int q = 0; q < 8; ++q) { gv[q] = (__bf16)0.f; uv[q] = (__bf16)0.f; }
      }
      *reinterpret_cast<bf8v*>(reinterpret_cast<char*>(Bgs) + off) = gv;
      *reinterpret_cast<bf8v*>(reinterpret_cast<char*>(Bus) + off) = uv;
    }
    __syncthreads();
#pragma unroll
    for (int kk = 0; kk < 2; ++kk) {
      int kb = kk * 64 + ((lane >> 4) << 4);
      bf8v af[4];
#pragma unroll
      for (int m = 0; m < 4; ++m) {
        int row = wm * 64 + m * 16 + (lane & 15);
        af[m] = *reinterpret_cast<const bf8v*>(
            reinterpret_cast<const char*>(As) + ((row * 128 + kb) ^ ((row & 7) << 4)));
      }
      bf8v bg[2], bu[2];
#pragma unroll
      for (int n = 0; n < 2; ++n) {
        int row = wn * 32 + n * 16 + (lane & 15);
        int off = (row * 128 + kb) ^ ((row & 7) << 4);
        bg[n] = *reinterpret_cast<const bf8v*>(reinterpret_cast<const char*>(Bgs) + off);
        bu[n] = *reinterpret_cast<const bf8v*>(reinterpret_cast<const char*>(Bus) + off);
      }
#pragma unroll
      for (int m = 0; m < 4; ++m)
#pragma unroll
        for (int n = 0; n < 2; ++n) {
          accG[m][n] = mfma_bf16(af[m], bg[n], accG[m][n]);
          accU[m][n] = mfma_bf16(af[m], bu[n], accU[m][n]);
        }
    }
    __syncthreads();
  }
  __bf16* hb = Hbuf + (size_t)e * CAP * HP;
#pragma unroll
  for (int m = 0; m < 4; ++m)
#pragma unroll
    for (int n = 0; n < 2; ++n)
#pragma unroll
      for (int j = 0; j < 4; ++j) {
        int row = m0 + wm * 64 + m * 16 + ((lane >> 4) << 2) + j;
        int col = n0 + wn * 32 + n * 16 + (lane & 15);
        float g = accG[m][n][j];
        float u = accU[m][n][j];
        float h = g / (1.f + expf(-g)) * u;
        hb[(size_t)row * HP + col] = (__bf16)h;
      }
}

__global__ __launch_bounds__(256) void gemm2_down_f32(
    const __bf16* __restrict__ Hbuf, const float* __restrict__ wd,
    const int* __restrict__ ecnt, const int* __restrict__ etok, const float* __restrict__ ep,
    float* __restrict__ out) {
  int bid = blockIdx.x;
  int wgid = (bid & 7) * 128 + (bid >> 3);
  int pm = wgid & 7;
  int pn = (wgid >> 3) & 15;
  int e  = wgid >> 7;
  int ne = ecnt[e];
  int m0 = pm * 128, n0 = pn * 64;
  if (m0 >= ne) return;
  __shared__ __align__(16) __bf16 As[128 * 64];
  __shared__ __align__(16) __bf16 Bs[64 * 64];
  int tid = threadIdx.x;
  int lane = tid & 63, wave = tid >> 6;
  int wm = wave >> 1, wn = wave & 1;
  f4 acc[4][2];
#pragma unroll
  for (int m = 0; m < 4; ++m)
#pragma unroll
    for (int n = 0; n < 2; ++n) acc[m][n] = (f4){0,0,0,0};
  const __bf16* Abase = Hbuf + (size_t)(e * CAP + m0) * HP;
  const float* Bbase = wd + (size_t)e * DM * HD;
  for (int kt = 0; kt < HP / 64; ++kt) {
    int k0 = kt * 64;
#pragma unroll
    for (int i = 0; i < 4; ++i) {
      int c = tid + 256 * i;
      int row = c >> 3, c8 = c & 7;
      u4v v = *reinterpret_cast<const u4v*>(Abase + (size_t)row * HP + k0 + c8 * 8);
      int off = (row * 128 + c8 * 16) ^ ((row & 7) << 4);
      *reinterpret_cast<u4v*>(reinterpret_cast<char*>(As) + off) = v;
    }
#pragma unroll
    for (int i = 0; i < 2; ++i) {
      int c = tid + 256 * i;
      int row = c >> 3, c8 = c & 7;
      int nn = n0 + row;
      int kg = k0 + c8 * 8;
      int off = (row * 128 + c8 * 16) ^ ((row & 7) << 4);
      bf8v bv;
      const float* src = Bbase + (size_t)nn * HD + kg;
      if (kg + 8 <= HD) {
        f2 q0 = *reinterpret_cast<const f2*>(src);
        f2 q1 = *reinterpret_cast<const f2*>(src + 2);
        f2 q2 = *reinterpret_cast<const f2*>(src + 4);
        f2 q3 = *reinterpret_cast<const f2*>(src + 6);
        bv[0] = (__bf16)q0[0]; bv[1] = (__bf16)q0[1]; bv[2] = (__bf16)q1[0]; bv[3] = (__bf16)q1[1];
        bv[4] = (__bf16)q2[0]; bv[5] = (__bf16)q2[1]; bv[6] = (__bf16)q3[0]; bv[7] = (__bf16)q3[1];
      } else {
#pragma unroll
        for (int q = 0; q < 8; ++q) bv[q] = (kg + q < HD) ? (__bf16)src[q] : (__bf16)0.f;
      }
      *reinterpret_cast<bf8v*>(reinterpret_cast<char*>(Bs) + off) = bv;
    }
    __syncthreads();
#pragma unroll
    for (int kk = 0; kk < 2; ++kk) {
      int kb = kk * 64 + ((lane >> 4) << 4);
      bf8v af[4];
#pragma unroll
      for (int m = 0; m < 4; ++m) {
        int row = wm * 64 + m * 16 + (lane & 15);
        af[m] = *reinterpret_cast<const bf8v*>(
            reinterpret_cast<const char*>(As) + ((row * 128 + kb) ^ ((row & 7) << 4)));
      }
      bf8v bfr[2];
#pragma unroll
      for (int n = 0; n < 2; ++n) {
        int row = wn * 32 + n * 16 + (lane & 15);
        bfr[n] = *reinterpret_cast<const bf8v*>(
            reinterpret_cast<const char*>(Bs) + ((row * 128 + kb) ^ ((row & 7) << 4)));
      }
#pragma unroll
      for (int m = 0; m < 4; ++m)
#pragma unroll
        for (int n = 0; n < 2; ++n)
          acc[m][n] = mfma_bf16(af[m], bfr[n], acc[m][n]);
    }
    __syncthreads();
  }
#pragma unroll
  for (int m = 0; m < 4; ++m)
#pragma unroll
    for (int j = 0; j < 4; ++j) {
      int row = m0 + wm * 64 + m * 16 + ((lane >> 4) << 2) + j;
      if (row < ne) {
        float p  = ep[e * CAP + row];
        int tok  = etok[e * CAP + row] >> 1;
        float* orow = out + (size_t)tok * DM;
#pragma unroll
        for (int n = 0; n < 2; ++n) {
          int col = n0 + wn * 32 + n * 16 + (lane & 15);
          atomicAdd(orow + col, acc[m][n][j] * p);
        }
      }
    }
}

// ---------------- launch ----------------
extern "C" void kernel_launch(void* const* d_in, const int* in_sizes, int n_in,
                              void* d_out, int out_size, void* d_ws, size_t ws_size,
                              hipStream_t stream) {
  const float* x     = (const float*)d_in[0];
  const float* gw    = (const float*)d_in[1];
  const float* wgate = (const float*)d_in[2];
  const float* wup   = (const float*)d_in[3];
  const float* wdown = (const float*)d_in[4];
  float* out = (float*)d_out;
  char* ws = (char*)d_ws;

  float* elp   = (float*)(ws + 0);          // 524288
  int*   elpos = (int*)  (ws + 524288);     // 524288
  int*   cnt   = (int*)  (ws + 1048576);    // 256
  int*   etok  = (int*)  (ws + 1048832);    // 32768
  float* ep    = (float*)(ws + 1081600);    // 32768
  int*   ecnt  = (int*)  (ws + 1114368);    // 256
  __bf16* Xe   = (__bf16*)(ws + 1114624);   // 16777216 -> 17891840
  __bf16* Hbuf = (__bf16*)(ws + 17891840);  // 45088768 -> 62980608
  __bf16* wgb  = (__bf16*)(ws + 62980608);  // 8*2752*1024*2 = 45088768 -> 108069376
  __bf16* wub  = (__bf16*)(ws + 108069376); // 45088768 -> 153158144
  __bf16* wdb  = (__bf16*)(ws + 153158144); // 8*1024*2752*2 = 45088768 -> 198246912
  const size_t NEEDED = 198246912ULL;

  hipMemsetAsync(out, 0, (size_t)NTOK * DM * sizeof(float), stream);
  hipMemsetAsync(cnt, 0, NE * sizeof(int), stream);
  router_kernel<<<NTOK / 4, 256, 0, stream>>>(x, gw, cnt, elp, elpos);
  rank_kernel<<<NE * RCHUNKS, 256, 0, stream>>>(cnt, elp, elpos, etok, ep, ecnt);
  gather_kernel<<<NE * CAP, 256, 0, stream>>>(x, etok, ecnt, Xe);

  if (ws_size >= NEEDED) {
    dim3 gcv(1376, NE);   // HP*DM/8/256 = 1376
    convert_gu<<<gcv, 256, 0, stream>>>(wgate, wgb);
    convert_gu<<<gcv, 256, 0, stream>>>(wup, wub);
    convert_wd<<<gcv, 256, 0, stream>>>(wdown, wdb);
    gemm1_swiglu_bf<<<8 * 43 * 8, 256, 0, stream>>>(Xe, wgb, wub, ecnt, Hbuf);
    gemm2_down_bf<<<8 * 16 * 8, 256, 0, stream>>>(Hbuf, wdb, ecnt, etok, ep, out);
  } else {
    gemm1_swiglu_f32<<<8 * 43 * 8, 256, 0, stream>>>(Xe, wgate, wup, ecnt, Hbuf);
    gemm2_down_f32<<<8 * 16 * 8, 256, 0, stream>>>(Hbuf, wdown, ecnt, etok, ep, out);
  }
}

// Round 4
// 436.826 us; speedup vs baseline: 2.2195x; 1.3971x over previous
//
#include <hip/hip_runtime.h>

// MoE: T=8192, D=1024, E=8, top-2, H=2730 (pad 2752), capacity=1024.
// Pipeline: memset(out) -> router (atomic-free, dense u64 recs)
//   -> rank_select (per-expert LDS append + count-rank) -> gather(bf16)
//   -> convert weights fp32->bf16 -> gemm1 (swiglu, gload_lds+swizzle)
//   -> gemm2 (down, gload_lds+swizzle). Fallback fp32-weight GEMMs if ws too small.

typedef float  f4  __attribute__((ext_vector_type(4)));
typedef float  f2  __attribute__((ext_vector_type(2)));
typedef __bf16 bf8v __attribute__((ext_vector_type(8)));
typedef __bf16 bf4v __attribute__((ext_vector_type(4)));
typedef unsigned int u32;
typedef unsigned long long u64;
typedef u32 u4v __attribute__((ext_vector_type(4)));

#define NTOK 8192
#define DM   1024
#define NE   8
#define HD   2730
#define HP   2752
#define CAP  1024

__device__ __forceinline__ f4 mfma_bf16(bf8v a, bf8v b, f4 c) {
  return __builtin_amdgcn_mfma_f32_16x16x32_bf16(a, b, c, 0, 0, 0);
}

__device__ __forceinline__ void gl_lds16(const void* g, void* l) {
  __builtin_amdgcn_global_load_lds(
      (const __attribute__((address_space(1))) unsigned int*)g,
      (__attribute__((address_space(3))) unsigned int*)l, 16, 0, 0);
}

// ---------------- router: logits + top-2 + softmax -> dense u64 records (no atomics) ----------------
// rec = (p_bits << 32) | (0xFFFFFFFF - (flat_pos*8 | expert)); u64 '>' == (p desc, pos asc).
__global__ __launch_bounds__(256) void router_kernel(
    const float* __restrict__ x, const float* __restrict__ gw, u64* __restrict__ recs) {
  __shared__ float gws[NE][DM];
  int tid = threadIdx.x;
  for (int i = tid * 4; i < NE * DM; i += 1024)
    *reinterpret_cast<f4*>(&gws[0][i]) = *reinterpret_cast<const f4*>(gw + i);
  __syncthreads();
  int lane = tid & 63, wave = tid >> 6;
  int tbase = blockIdx.x * 16 + wave * 4;
#pragma unroll
  for (int tt = 0; tt < 4; ++tt) {
    int t = tbase + tt;
    const f4* xr = reinterpret_cast<const f4*>(x + (size_t)t * DM);
    float acc[NE];
#pragma unroll
    for (int e = 0; e < NE; ++e) acc[e] = 0.f;
#pragma unroll
    for (int i = 0; i < 4; ++i) {
      f4 xv = xr[i * 64 + lane];
#pragma unroll
      for (int e = 0; e < NE; ++e) {
        f4 gv = *reinterpret_cast<const f4*>(&gws[e][i * 256 + lane * 4]);
        acc[e] += xv[0] * gv[0] + xv[1] * gv[1] + xv[2] * gv[2] + xv[3] * gv[3];
      }
    }
#pragma unroll
    for (int e = 0; e < NE; ++e) {
      float v = acc[e];
#pragma unroll
      for (int off = 32; off > 0; off >>= 1) v += __shfl_xor(v, off);
      acc[e] = v;
    }
    if (lane == 0) {
      float l0 = -1e30f, l1 = -1e30f; int i0 = 0, i1 = 0;
#pragma unroll
      for (int e = 0; e < NE; ++e) {
        float v = acc[e];
        if (v > l0)      { l1 = l0; i1 = i0; l0 = v; i0 = e; }
        else if (v > l1) { l1 = v; i1 = e; }
      }
      float e1 = expf(l1 - l0);
      float s  = 1.f + e1;
      float p0 = 1.f / s, p1 = e1 / s;
      float s2 = p0 + p1;
      p0 /= s2; p1 /= s2;
      u32 pf0 = 0xFFFFFFFFu - (((u32)(2 * t)     << 3) | (u32)i0);
      u32 pf1 = 0xFFFFFFFFu - (((u32)(2 * t + 1) << 3) | (u32)i1);
      recs[2 * t]     = ((u64)__float_as_uint(p0) << 32) | pf0;
      recs[2 * t + 1] = ((u64)__float_as_uint(p1) << 32) | pf1;
    }
  }
}

// ---------------- rank_select: per-expert append (wave-aggregated LDS atomic) + count-rank ----------------
__global__ __launch_bounds__(1024) void rank_select(
    const u64* __restrict__ recs, int* __restrict__ etok, float* __restrict__ ep,
    int* __restrict__ ecnt) {
  __shared__ u64 keys[8192];   // n <= 8192 structurally (top-2 experts distinct per token)
  __shared__ int lcnt;
  int e = blockIdx.x;
  int tid = threadIdx.x;
  int lane = tid & 63;
  if (tid == 0) lcnt = 0;
  __syncthreads();
  for (int s = tid; s < 2 * NTOK; s += 1024) {
    u64 r = recs[s];
    bool m = ((0xFFFFFFFFu - (u32)r) & 7u) == (u32)e;
    u64 mask = __ballot(m);
    int base = 0;
    if (lane == 0 && mask) base = atomicAdd(&lcnt, __popcll(mask));
    base = __shfl(base, 0);
    if (m) {
      int off = __popcll(mask & ((1ull << lane) - 1ull));
      keys[base + off] = r;
    }
  }
  __syncthreads();
  int n = lcnt;
  for (int i = tid; i < n; i += 1024) {
    u64 ki = keys[i];
    int r = 0;
#pragma unroll 8
    for (int j = 0; j < n; ++j) r += (keys[j] > ki);
    if (r < CAP) {
      u32 v = 0xFFFFFFFFu - (u32)ki;
      etok[e * CAP + r] = (int)(v >> 3);                    // flat pos = 2t+k
      ep[e * CAP + r]   = __uint_as_float((u32)(ki >> 32));
    }
  }
  if (tid == 0) ecnt[e] = n < CAP ? n : CAP;
}

// ---------------- gather kept tokens -> bf16 ----------------
__global__ __launch_bounds__(256) void gather_kernel(
    const float* __restrict__ x, const int* __restrict__ etok, const int* __restrict__ ecnt,
    __bf16* __restrict__ Xe) {
  int e = blockIdx.x >> 10;
  int r = blockIdx.x & 1023;
  __bf16* dst = Xe + ((size_t)(e * CAP + r)) * DM;
  int tid = threadIdx.x;
  bf4v o;
  if (r < ecnt[e]) {
    int tok = etok[e * CAP + r] >> 1;
    f4 v = reinterpret_cast<const f4*>(x + (size_t)tok * DM)[tid];
    o[0] = (__bf16)v[0]; o[1] = (__bf16)v[1]; o[2] = (__bf16)v[2]; o[3] = (__bf16)v[3];
  } else {
    o[0] = (__bf16)0.f; o[1] = (__bf16)0.f; o[2] = (__bf16)0.f; o[3] = (__bf16)0.f;
  }
  reinterpret_cast<bf4v*>(dst)[tid] = o;
}

// ---------------- weight conversion fp32 -> bf16 ----------------
__global__ __launch_bounds__(256) void convert_gu(
    const float* __restrict__ src, __bf16* __restrict__ dst) {
  int e = blockIdx.y;
  int idx = blockIdx.x * 256 + threadIdx.x;
  int row = idx >> 7;
  int c = (idx & 127) << 3;
  bf8v o;
  if (row < HD) {
    const float* s = src + ((size_t)e * HD + row) * DM + c;
    f4 a = *reinterpret_cast<const f4*>(s);
    f4 b = *reinterpret_cast<const f4*>(s + 4);
#pragma unroll
    for (int q = 0; q < 4; ++q) { o[q] = (__bf16)a[q]; o[q + 4] = (__bf16)b[q]; }
  } else {
#pragma unroll
    for (int q = 0; q < 8; ++q) o[q] = (__bf16)0.f;
  }
  *reinterpret_cast<bf8v*>(dst + ((size_t)e * HP + row) * DM + c) = o;
}

__global__ __launch_bounds__(256) void convert_wd(
    const float* __restrict__ src, __bf16* __restrict__ dst) {
  int e = blockIdx.y;
  int idx = blockIdx.x * 256 + threadIdx.x;
  int row = idx / 344;
  int c = (idx % 344) << 3;
  const float* s = src + ((size_t)e * DM + row) * HD + c;
  bf8v o;
  if (c + 8 <= HD) {
    f2 q0 = *reinterpret_cast<const f2*>(s);
    f2 q1 = *reinterpret_cast<const f2*>(s + 2);
    f2 q2 = *reinterpret_cast<const f2*>(s + 4);
    f2 q3 = *reinterpret_cast<const f2*>(s + 6);
    o[0] = (__bf16)q0[0]; o[1] = (__bf16)q0[1]; o[2] = (__bf16)q1[0]; o[3] = (__bf16)q1[1];
    o[4] = (__bf16)q2[0]; o[5] = (__bf16)q2[1]; o[6] = (__bf16)q3[0]; o[7] = (__bf16)q3[1];
  } else {
#pragma unroll
    for (int q = 0; q < 8; ++q) o[q] = (c + q < HD) ? (__bf16)s[q] : (__bf16)0.f;
  }
  *reinterpret_cast<bf8v*>(dst + ((size_t)e * DM + row) * HP + c) = o;
}

// ============ bf16 GEMMs: gload_lds staging, both-sides XOR swizzle ============
__global__ __launch_bounds__(256) void gemm1_swiglu_bf(
    const __bf16* __restrict__ Xe, const __bf16* __restrict__ wgb, const __bf16* __restrict__ wub,
    const int* __restrict__ ecnt, __bf16* __restrict__ Hbuf) {
  int bid = blockIdx.x;                         // 2752 = 8 XCD * 344
  int wgid = (bid & 7) * 344 + (bid >> 3);      // each XCD owns one expert
  int pm = wgid & 7;
  int pn = (wgid >> 3) % 43;
  int e  = wgid / 344;
  int ne = ecnt[e];
  int m0 = pm * 128, n0 = pn * 64;
  if (m0 >= ne) return;

  __shared__ __align__(16) __bf16 As[128 * 64];
  __shared__ __align__(16) __bf16 Bgs[64 * 64];
  __shared__ __align__(16) __bf16 Bus[64 * 64];

  int tid = threadIdx.x;
  int lane = tid & 63, wave = tid >> 6;
  int wm = wave >> 1, wn = wave & 1;
  int lr = lane >> 3;
  int scol = (((lane & 7) << 4) ^ (lr << 4)) >> 1;

  f4 accG[4][2], accU[4][2];
#pragma unroll
  for (int m = 0; m < 4; ++m)
#pragma unroll
    for (int n = 0; n < 2; ++n) { accG[m][n] = (f4){0,0,0,0}; accU[m][n] = (f4){0,0,0,0}; }

  const __bf16* Ab = Xe + ((size_t)(e * CAP + m0)) * DM;
  const __bf16* Gb = wgb + (size_t)e * HP * DM + (size_t)n0 * DM;
  const __bf16* Ub = wub + (size_t)e * HP * DM + (size_t)n0 * DM;

  for (int kt = 0; kt < DM / 64; ++kt) {
    int k0 = kt * 64;
#pragma unroll
    for (int i = 0; i < 4; ++i) {
      int rb = i * 32 + wave * 8 + lr;
      gl_lds16(Ab + (size_t)rb * DM + k0 + scol, (char*)As + i * 4096 + wave * 1024);
    }
#pragma unroll
    for (int i = 0; i < 2; ++i) {
      int rb = i * 32 + wave * 8 + lr;
      gl_lds16(Gb + (size_t)rb * DM + k0 + scol, (char*)Bgs + i * 4096 + wave * 1024);
      gl_lds16(Ub + (size_t)rb * DM + k0 + scol, (char*)Bus + i * 4096 + wave * 1024);
    }
    __syncthreads();
#pragma unroll
    for (int kk = 0; kk < 2; ++kk) {
      int kb = kk * 64 + ((lane >> 4) << 4);
      bf8v af[4];
#pragma unroll
      for (int m = 0; m < 4; ++m) {
        int row = wm * 64 + m * 16 + (lane & 15);
        af[m] = *reinterpret_cast<const bf8v*>(
            reinterpret_cast<const char*>(As) + ((row * 128 + kb) ^ ((row & 7) << 4)));
      }
      bf8v bg[2], bu[2];
#pragma unroll
      for (int n = 0; n < 2; ++n) {
        int row = wn * 32 + n * 16 + (lane & 15);
        int off = (row * 128 + kb) ^ ((row & 7) << 4);
        bg[n] = *reinterpret_cast<const bf8v*>(reinterpret_cast<const char*>(Bgs) + off);
        bu[n] = *reinterpret_cast<const bf8v*>(reinterpret_cast<const char*>(Bus) + off);
      }
#pragma unroll
      for (int m = 0; m < 4; ++m)
#pragma unroll
        for (int n = 0; n < 2; ++n) {
          accG[m][n] = mfma_bf16(af[m], bg[n], accG[m][n]);
          accU[m][n] = mfma_bf16(af[m], bu[n], accU[m][n]);
        }
    }
    __syncthreads();
  }

  __bf16* hb = Hbuf + (size_t)e * CAP * HP;
#pragma unroll
  for (int m = 0; m < 4; ++m)
#pragma unroll
    for (int n = 0; n < 2; ++n)
#pragma unroll
      for (int j = 0; j < 4; ++j) {
        int row = m0 + wm * 64 + m * 16 + ((lane >> 4) << 2) + j;
        int col = n0 + wn * 32 + n * 16 + (lane & 15);
        float g = accG[m][n][j];
        float u = accU[m][n][j];
        float h = g / (1.f + expf(-g)) * u;
        hb[(size_t)row * HP + col] = (__bf16)h;
      }
}

__global__ __launch_bounds__(256) void gemm2_down_bf(
    const __bf16* __restrict__ Hbuf, const __bf16* __restrict__ wdb,
    const int* __restrict__ ecnt, const int* __restrict__ etok, const float* __restrict__ ep,
    float* __restrict__ out) {
  int bid = blockIdx.x;                        // 1024 = 8 XCD * 128
  int wgid = (bid & 7) * 128 + (bid >> 3);
  int pm = wgid & 7;
  int pn = (wgid >> 3) & 15;
  int e  = wgid >> 7;
  int ne = ecnt[e];
  int m0 = pm * 128, n0 = pn * 64;
  if (m0 >= ne) return;

  __shared__ __align__(16) __bf16 As[128 * 64];
  __shared__ __align__(16) __bf16 Bs[64 * 64];

  int tid = threadIdx.x;
  int lane = tid & 63, wave = tid >> 6;
  int wm = wave >> 1, wn = wave & 1;
  int lr = lane >> 3;
  int scol = (((lane & 7) << 4) ^ (lr << 4)) >> 1;

  f4 acc[4][2];
#pragma unroll
  for (int m = 0; m < 4; ++m)
#pragma unroll
    for (int n = 0; n < 2; ++n) acc[m][n] = (f4){0,0,0,0};

  const __bf16* Ab = Hbuf + (size_t)(e * CAP + m0) * HP;
  const __bf16* Bb = wdb + (size_t)e * DM * HP + (size_t)n0 * HP;

  for (int kt = 0; kt < HP / 64; ++kt) {
    int k0 = kt * 64;
#pragma unroll
    for (int i = 0; i < 4; ++i) {
      int rb = i * 32 + wave * 8 + lr;
      gl_lds16(Ab + (size_t)rb * HP + k0 + scol, (char*)As + i * 4096 + wave * 1024);
    }
#pragma unroll
    for (int i = 0; i < 2; ++i) {
      int rb = i * 32 + wave * 8 + lr;
      gl_lds16(Bb + (size_t)rb * HP + k0 + scol, (char*)Bs + i * 4096 + wave * 1024);
    }
    __syncthreads();
#pragma unroll
    for (int kk = 0; kk < 2; ++kk) {
      int kb = kk * 64 + ((lane >> 4) << 4);
      bf8v af[4];
#pragma unroll
      for (int m = 0; m < 4; ++m) {
        int row = wm * 64 + m * 16 + (lane & 15);
        af[m] = *reinterpret_cast<const bf8v*>(
            reinterpret_cast<const char*>(As) + ((row * 128 + kb) ^ ((row & 7) << 4)));
      }
      bf8v bfr[2];
#pragma unroll
      for (int n = 0; n < 2; ++n) {
        int row = wn * 32 + n * 16 + (lane & 15);
        bfr[n] = *reinterpret_cast<const bf8v*>(
            reinterpret_cast<const char*>(Bs) + ((row * 128 + kb) ^ ((row & 7) << 4)));
      }
#pragma unroll
      for (int m = 0; m < 4; ++m)
#pragma unroll
        for (int n = 0; n < 2; ++n)
          acc[m][n] = mfma_bf16(af[m], bfr[n], acc[m][n]);
    }
    __syncthreads();
  }

#pragma unroll
  for (int m = 0; m < 4; ++m)
#pragma unroll
    for (int j = 0; j < 4; ++j) {
      int row = m0 + wm * 64 + m * 16 + ((lane >> 4) << 2) + j;
      if (row < ne) {
        float p  = ep[e * CAP + row];
        int tok  = etok[e * CAP + row] >> 1;
        float* orow = out + (size_t)tok * DM;
#pragma unroll
        for (int n = 0; n < 2; ++n) {
          int col = n0 + wn * 32 + n * 16 + (lane & 15);
          atomicAdd(orow + col, acc[m][n][j] * p);
        }
      }
    }
}

// ============ fallback fp32-weight GEMMs ============
__global__ __launch_bounds__(256) void gemm1_swiglu_f32(
    const __bf16* __restrict__ Xe, const float* __restrict__ wg, const float* __restrict__ wu,
    const int* __restrict__ ecnt, __bf16* __restrict__ Hbuf) {
  int bid = blockIdx.x;
  int wgid = (bid & 7) * 344 + (bid >> 3);
  int pm = wgid & 7;
  int pn = (wgid >> 3) % 43;
  int e  = wgid / 344;
  int ne = ecnt[e];
  int m0 = pm * 128, n0 = pn * 64;
  if (m0 >= ne) return;
  __shared__ __align__(16) __bf16 As[128 * 64];
  __shared__ __align__(16) __bf16 Bgs[64 * 64];
  __shared__ __align__(16) __bf16 Bus[64 * 64];
  int tid = threadIdx.x;
  int lane = tid & 63, wave = tid >> 6;
  int wm = wave >> 1, wn = wave & 1;
  f4 accG[4][2], accU[4][2];
#pragma unroll
  for (int m = 0; m < 4; ++m)
#pragma unroll
    for (int n = 0; n < 2; ++n) { accG[m][n] = (f4){0,0,0,0}; accU[m][n] = (f4){0,0,0,0}; }
  const __bf16* Abase = Xe + ((size_t)(e * CAP + m0)) * DM;
  const float* Gbase = wg + (size_t)e * HD * DM;
  const float* Ubase = wu + (size_t)e * HD * DM;
  for (int kt = 0; kt < DM / 64; ++kt) {
    int k0 = kt * 64;
#pragma unroll
    for (int i = 0; i < 4; ++i) {
      int c = tid + 256 * i;
      int row = c >> 3, c8 = c & 7;
      u4v v = *reinterpret_cast<const u4v*>(Abase + (size_t)row * DM + k0 + c8 * 8);
      int off = (row * 128 + c8 * 16) ^ ((row & 7) << 4);
      *reinterpret_cast<u4v*>(reinterpret_cast<char*>(As) + off) = v;
    }
#pragma unroll
    for (int i = 0; i < 2; ++i) {
      int c = tid + 256 * i;
      int row = c >> 3, c8 = c & 7;
      int ng = n0 + row;
      int off = (row * 128 + c8 * 16) ^ ((row & 7) << 4);
      bf8v gv, uv;
      if (ng < HD) {
        const float* gs = Gbase + (size_t)ng * DM + k0 + c8 * 8;
        const float* us = Ubase + (size_t)ng * DM + k0 + c8 * 8;
        f4 a0 = *reinterpret_cast<const f4*>(gs);
        f4 a1 = *reinterpret_cast<const f4*>(gs + 4);
        f4 b0 = *reinterpret_cast<const f4*>(us);
        f4 b1 = *reinterpret_cast<const f4*>(us + 4);
#pragma unroll
        for (int q = 0; q < 4; ++q) {
          gv[q] = (__bf16)a0[q]; gv[q + 4] = (__bf16)a1[q];
          uv[q] = (__bf16)b0[q]; uv[q + 4] = (__bf16)b1[q];
        }
      } else {
#pragma unroll
        for (int q = 0; q < 8; ++q) { gv[q] = (__bf16)0.f; uv[q] = (__bf16)0.f; }
      }
      *reinterpret_cast<bf8v*>(reinterpret_cast<char*>(Bgs) + off) = gv;
      *reinterpret_cast<bf8v*>(reinterpret_cast<char*>(Bus) + off) = uv;
    }
    __syncthreads();
#pragma unroll
    for (int kk = 0; kk < 2; ++kk) {
      int kb = kk * 64 + ((lane >> 4) << 4);
      bf8v af[4];
#pragma unroll
      for (int m = 0; m < 4; ++m) {
        int row = wm * 64 + m * 16 + (lane & 15);
        af[m] = *reinterpret_cast<const bf8v*>(
            reinterpret_cast<const char*>(As) + ((row * 128 + kb) ^ ((row & 7) << 4)));
      }
      bf8v bg[2], bu[2];
#pragma unroll
      for (int n = 0; n < 2; ++n) {
        int row = wn * 32 + n * 16 + (lane & 15);
        int off = (row * 128 + kb) ^ ((row & 7) << 4);
        bg[n] = *reinterpret_cast<const bf8v*>(reinterpret_cast<const char*>(Bgs) + off);
        bu[n] = *reinterpret_cast<const bf8v*>(reinterpret_cast<const char*>(Bus) + off);
      }
#pragma unroll
      for (int m = 0; m < 4; ++m)
#pragma unroll
        for (int n = 0; n < 2; ++n) {
          accG[m][n] = mfma_bf16(af[m], bg[n], accG[m][n]);
          accU[m][n] = mfma_bf16(af[m], bu[n], accU[m][n]);
        }
    }
    __syncthreads();
  }
  __bf16* hb = Hbuf + (size_t)e * CAP * HP;
#pragma unroll
  for (int m = 0; m < 4; ++m)
#pragma unroll
    for (int n = 0; n < 2; ++n)
#pragma unroll
      for (int j = 0; j < 4; ++j) {
        int row = m0 + wm * 64 + m * 16 + ((lane >> 4) << 2) + j;
        int col = n0 + wn * 32 + n * 16 + (lane & 15);
        float g = accG[m][n][j];
        float u = accU[m][n][j];
        float h = g / (1.f + expf(-g)) * u;
        hb[(size_t)row * HP + col] = (__bf16)h;
      }
}

__global__ __launch_bounds__(256) void gemm2_down_f32(
    const __bf16* __restrict__ Hbuf, const float* __restrict__ wd,
    const int* __restrict__ ecnt, const int* __restrict__ etok, const float* __restrict__ ep,
    float* __restrict__ out) {
  int bid = blockIdx.x;
  int wgid = (bid & 7) * 128 + (bid >> 3);
  int pm = wgid & 7;
  int pn = (wgid >> 3) & 15;
  int e  = wgid >> 7;
  int ne = ecnt[e];
  int m0 = pm * 128, n0 = pn * 64;
  if (m0 >= ne) return;
  __shared__ __align__(16) __bf16 As[128 * 64];
  __shared__ __align__(16) __bf16 Bs[64 * 64];
  int tid = threadIdx.x;
  int lane = tid & 63, wave = tid >> 6;
  int wm = wave >> 1, wn = wave & 1;
  f4 acc[4][2];
#pragma unroll
  for (int m = 0; m < 4; ++m)
#pragma unroll
    for (int n = 0; n < 2; ++n) acc[m][n] = (f4){0,0,0,0};
  const __bf16* Abase = Hbuf + (size_t)(e * CAP + m0) * HP;
  const float* Bbase = wd + (size_t)e * DM * HD;
  for (int kt = 0; kt < HP / 64; ++kt) {
    int k0 = kt * 64;
#pragma unroll
    for (int i = 0; i < 4; ++i) {
      int c = tid + 256 * i;
      int row = c >> 3, c8 = c & 7;
      u4v v = *reinterpret_cast<const u4v*>(Abase + (size_t)row * HP + k0 + c8 * 8);
      int off = (row * 128 + c8 * 16) ^ ((row & 7) << 4);
      *reinterpret_cast<u4v*>(reinterpret_cast<char*>(As) + off) = v;
    }
#pragma unroll
    for (int i = 0; i < 2; ++i) {
      int c = tid + 256 * i;
      int row = c >> 3, c8 = c & 7;
      int nn = n0 + row;
      int kg = k0 + c8 * 8;
      int off = (row * 128 + c8 * 16) ^ ((row & 7) << 4);
      bf8v bv;
      const float* src = Bbase + (size_t)nn * HD + kg;
      if (kg + 8 <= HD) {
        f2 q0 = *reinterpret_cast<const f2*>(src);
        f2 q1 = *reinterpret_cast<const f2*>(src + 2);
        f2 q2 = *reinterpret_cast<const f2*>(src + 4);
        f2 q3 = *reinterpret_cast<const f2*>(src + 6);
        bv[0] = (__bf16)q0[0]; bv[1] = (__bf16)q0[1]; bv[2] = (__bf16)q1[0]; bv[3] = (__bf16)q1[1];
        bv[4] = (__bf16)q2[0]; bv[5] = (__bf16)q2[1]; bv[6] = (__bf16)q3[0]; bv[7] = (__bf16)q3[1];
      } else {
#pragma unroll
        for (int q = 0; q < 8; ++q) bv[q] = (kg + q < HD) ? (__bf16)src[q] : (__bf16)0.f;
      }
      *reinterpret_cast<bf8v*>(reinterpret_cast<char*>(Bs) + off) = bv;
    }
    __syncthreads();
#pragma unroll
    for (int kk = 0; kk < 2; ++kk) {
      int kb = kk * 64 + ((lane >> 4) << 4);
      bf8v af[4];
#pragma unroll
      for (int m = 0; m < 4; ++m) {
        int row = wm * 64 + m * 16 + (lane & 15);
        af[m] = *reinterpret_cast<const bf8v*>(
            reinterpret_cast<const char*>(As) + ((row * 128 + kb) ^ ((row & 7) << 4)));
      }
      bf8v bfr[2];
#pragma unroll
      for (int n = 0; n < 2; ++n) {
        int row = wn * 32 + n * 16 + (lane & 15);
        bfr[n] = *reinterpret_cast<const bf8v*>(
            reinterpret_cast<const char*>(Bs) + ((row * 128 + kb) ^ ((row & 7) << 4)));
      }
#pragma unroll
      for (int m = 0; m < 4; ++m)
#pragma unroll
        for (int n = 0; n < 2; ++n)
          acc[m][n] = mfma_bf16(af[m], bfr[n], acc[m][n]);
    }
    __syncthreads();
  }
#pragma unroll
  for (int m = 0; m < 4; ++m)
#pragma unroll
    for (int j = 0; j < 4; ++j) {
      int row = m0 + wm * 64 + m * 16 + ((lane >> 4) << 2) + j;
      if (row < ne) {
        float p  = ep[e * CAP + row];
        int tok  = etok[e * CAP + row] >> 1;
        float* orow = out + (size_t)tok * DM;
#pragma unroll
        for (int n = 0; n < 2; ++n) {
          int col = n0 + wn * 32 + n * 16 + (lane & 15);
          atomicAdd(orow + col, acc[m][n][j] * p);
        }
      }
    }
}

// ---------------- launch ----------------
extern "C" void kernel_launch(void* const* d_in, const int* in_sizes, int n_in,
                              void* d_out, int out_size, void* d_ws, size_t ws_size,
                              hipStream_t stream) {
  const float* x     = (const float*)d_in[0];
  const float* gw    = (const float*)d_in[1];
  const float* wgate = (const float*)d_in[2];
  const float* wup   = (const float*)d_in[3];
  const float* wdown = (const float*)d_in[4];
  float* out = (float*)d_out;
  char* ws = (char*)d_ws;

  u64*   recs = (u64*)  (ws + 0);           // 16384*8 = 131072
  int*   etok = (int*)  (ws + 131072);      // 32768
  float* ep   = (float*)(ws + 163840);      // 32768
  int*   ecnt = (int*)  (ws + 196608);      // 256
  __bf16* Xe  = (__bf16*)(ws + 196864);     // 16777216 -> 16974080
  __bf16* Hbuf= (__bf16*)(ws + 16974080);   // 45088768 -> 62062848
  __bf16* wgb = (__bf16*)(ws + 62062848);   // 45088768 -> 107151616
  __bf16* wub = (__bf16*)(ws + 107151616);  // 45088768 -> 152240384
  __bf16* wdb = (__bf16*)(ws + 152240384);  // 45088768 -> 197329152
  const size_t NEEDED = 197329152ULL;

  hipMemsetAsync(out, 0, (size_t)NTOK * DM * sizeof(float), stream);
  router_kernel<<<NTOK / 16, 256, 0, stream>>>(x, gw, recs);
  rank_select<<<NE, 1024, 0, stream>>>(recs, etok, ep, ecnt);
  gather_kernel<<<NE * CAP, 256, 0, stream>>>(x, etok, ecnt, Xe);

  if (ws_size >= NEEDED) {
    dim3 gcv(1376, NE);
    convert_gu<<<gcv, 256, 0, stream>>>(wgate, wgb);
    convert_gu<<<gcv, 256, 0, stream>>>(wup, wub);
    convert_wd<<<gcv, 256, 0, stream>>>(wdown, wdb);
    gemm1_swiglu_bf<<<8 * 43 * 8, 256, 0, stream>>>(Xe, wgb, wub, ecnt, Hbuf);
    gemm2_down_bf<<<8 * 16 * 8, 256, 0, stream>>>(Hbuf, wdb, ecnt, etok, ep, out);
  } else {
    gemm1_swiglu_f32<<<8 * 43 * 8, 256, 0, stream>>>(Xe, wgate, wup, ecnt, Hbuf);
    gemm2_down_f32<<<8 * 16 * 8, 256, 0, stream>>>(Hbuf, wdown, ecnt, etok, ep, out);
  }
}